// Round 7
// baseline (193.567 us; speedup 1.0000x reference)
//
#include <hip/hip_runtime.h>

// RegLoss: l1(masked preds, targets) + 0.1 * mse(masked edge directions)
// preds, targets: [128, 1024, 151] fp32. Output: 1 fp32 scalar.
//
// Identities:
//   targets * (targets != 0) == targets       (masking targets is identity)
//   (m*pd - m*td)^2 == m*(pd - td)^2          (m in {0,1})
//   diff/(len+tiny) == (d2 > 0 ? diff*rsq(d2) : 0)  (~1e-7 rel; thresh 2.4e-2)
//
// R13: LANE = ROW -- kill the scalar gather. Ablation history: R6-R11
// (LDS-staged, every pipeline variant) and R12 (no LDS, global gather)
// all land at 62-67us with VALU <20%, LDS conflicts either 1.87M or 0,
// occupancy 31-65% (irrelevant), HBM irrelevant (L3-resident dispatches
// identical). The one invariant: every version gathered edge operands
// scalar-per-lane -- ~705 scattered wave-instructions per 64 rows through
// a serializing pipe (LDS issue in R6-R11, texture-address unit in R12).
// That gather is the bottleneck no PMC in our set names directly.
//
// New mapping: lane l owns row (l&7); edge work split over 8 lane-groups
// (g = l>>3), 6 rounds of e = g + 8*j. Row stride 151 dwords is ODD =>
// lane-l accesses at a common offset hit (l*151+off)%32 = all 32 banks
// exactly twice => conflict-free (2-way free, m136). One ds_read wave-instr
// now feeds 64 (row,edge) operand reads: ~330 DS instrs per 64 rows vs
// ~705 scattered + 1.87M conflict cycles before. Zero per-task addr math.
// Staging: coalesced float4 -> l1 from regs -> ds_write_b128 (linear,
// 9.7KB/wave slab). 38.9KB/block -> 4 blocks/CU, 16 waves/CU.
// Forward model per CU: ~42K cyc VALU + ~25K cyc DS => VALU-bound ~20us.
//
// Pre-committed: SQ_LDS_BANK_CONFLICT 1.87M -> <100K (else experiment
// void); VALUBusy -> 35-55%; FETCH ~78MB, WRITE ~130KB. Theory right =>
// main 28-42us. Conflicts drop + VALU up + duration unchanged => declare
// roofline next round.

#define N_ROWS   (128 * 1024)
#define ROW      151
#define N_EDGES  47
#define GRID     2048
#define BLOCK    256
#define ROWS_PER_WAVE 8
#define WAVE_DW  (ROWS_PER_WAVE * ROW)   // 1208 dwords per array per chunk
#define WAVE_F4  (WAVE_DW / 4)           // 302 float4 per array per chunk
#define CHUNKS   2                       // 2048blk*4w*8rows*2 = 131072 rows

#if __has_builtin(__builtin_amdgcn_rsqf)
__device__ __forceinline__ float fast_rsq(float x) { return __builtin_amdgcn_rsqf(x); }
#else
__device__ __forceinline__ float fast_rsq(float x) {
    float r; asm volatile("v_rsq_f32 %0, %1" : "=v"(r) : "v"(x)); return r;
}
#endif

// packed: low16 = parent*3 (dword offset in row), high16 = child*3
#define E(p, c) ((unsigned)((p) * 3) | ((unsigned)((c) * 3) << 16))
__constant__ unsigned c_edge[N_EDGES] = {
    E(0,1),  E(1,2),  E(2,3),  E(3,29), E(1,5),  E(5,6),  E(6,8),  E(8,9),
    E(8,13), E(8,17), E(8,21), E(8,25), E(9,10), E(10,11),E(11,12),E(13,14),
    E(14,15),E(15,16),E(17,18),E(18,19),E(19,20),E(21,22),E(22,23),E(23,24),
    E(25,26),E(26,27),E(27,28),E(29,30),E(29,34),E(29,38),E(29,42),E(29,46),
    E(30,31),E(31,32),E(32,33),E(34,35),E(35,36),E(36,37),E(38,39),E(39,40),
    E(40,41),E(42,43),E(43,44),E(44,45),E(46,47),E(47,48),E(48,49)};

__device__ __forceinline__ void acc_l1(float4 pv, float4 tv, float& l1) {
    float a0 = (tv.x != 0.f) ? pv.x : 0.f;
    float a1 = (tv.y != 0.f) ? pv.y : 0.f;
    float a2 = (tv.z != 0.f) ? pv.z : 0.f;
    float a3 = (tv.w != 0.f) ? pv.w : 0.f;
    l1 += fabsf(a0 - tv.x) + fabsf(a1 - tv.y)
        + fabsf(a2 - tv.z) + fabsf(a3 - tv.w);
}

__global__ __launch_bounds__(BLOCK, 4) void reg_loss_main(
        const float* __restrict__ preds, const float* __restrict__ targets,
        float* __restrict__ wsL, float* __restrict__ wsV) {
    // per-wave slab: [preds 1208 dw][targets 1208 dw] = 9664 B; x4 = 38.7 KB
    __shared__ float S[4][2 * WAVE_DW];
    __shared__ float redL[4], redV[4];

    const int t = threadIdx.x;
    const int lane = t & 63;
    const int wave = t >> 6;
    float* __restrict__ P = &S[wave][0];
    float* __restrict__ T = &S[wave][WAVE_DW];

    // lane = (edge-group g, row r); row stride 151 (odd) => conflict-free
    const int r = lane & 7;
    const int g = lane >> 3;

    // per-lane per-round addresses into the wave slab (row-relative, fixed)
    int aP[6], aC[6], aM[6];
    float act[6];
#pragma unroll
    for (int j = 0; j < 6; ++j) {
        int e = g + 8 * j;
        bool a = (e < N_EDGES);
        int ec = a ? e : (N_EDGES - 1);
        unsigned pk = c_edge[ec];
        aP[j]  = r * ROW + (int)(pk & 0xffff);
        aC[j]  = r * ROW + (int)(pk >> 16);
        aM[j]  = r * ROW + ec;
        act[j] = a ? 1.f : 0.f;
    }

    const long long wid = (long long)blockIdx.x * 4 + wave;
    float l1 = 0.f, vel = 0.f;

#pragma unroll
    for (int c = 0; c < CHUNKS; ++c) {
        const float4* __restrict__ gp4 = reinterpret_cast<const float4*>(
            preds + (wid * CHUNKS + c) * WAVE_DW);
        const float4* __restrict__ gt4 = reinterpret_cast<const float4*>(
            targets + (wid * CHUNKS + c) * WAVE_DW);
        float4* __restrict__ P4 = reinterpret_cast<float4*>(P);
        float4* __restrict__ T4 = reinterpret_cast<float4*>(T);

        // ---- stage 8 rows (coalesced) + l1 straight from registers ----
#pragma unroll
        for (int k = 0; k < 5; ++k) {
            int idx = lane + k * 64;
            if (k < 4 || lane < (WAVE_F4 - 256)) {   // 302: k=4 for lane<46
                float4 pv = gp4[idx];
                float4 tv = gt4[idx];
                P4[idx] = pv;
                T4[idx] = tv;
                acc_l1(pv, tv, l1);
            }
        }
        // same-wave DS pipe orders these writes vs the reads below; the
        // compiler inserts the lgkmcnt (single-wave-private slab, no bar).

        // ---- 8 rows x 47 edges: lane-parallel, conflict-free LDS ----
#pragma unroll
        for (int j = 0; j < 6; ++j) {
            int p = aP[j], q = aC[j], m = aM[j];
            float tpx = T[p], tpy = T[p + 1], tpz = T[p + 2];
            float tcx = T[q], tcy = T[q + 1], tcz = T[q + 2];
            float ppx = P[p], ppy = P[p + 1], ppz = P[p + 2];
            float pcx = P[q], pcy = P[q + 1], pcz = P[q + 2];
            float mg0 = T[m], mg1 = T[m + 47], mg2 = T[m + 94];
            // masked preds
            float apx = (tpx != 0.f) ? ppx : 0.f;
            float apy = (tpy != 0.f) ? ppy : 0.f;
            float apz = (tpz != 0.f) ? ppz : 0.f;
            float acx = (tcx != 0.f) ? pcx : 0.f;
            float acy = (tcy != 0.f) ? pcy : 0.f;
            float acz = (tcz != 0.f) ? pcz : 0.f;
            float pdx = apx - acx, pdy = apy - acy, pdz = apz - acz;
            float tdx = tpx - tcx, tdy = tpy - tcy, tdz = tpz - tcz;
            float pd2 = pdx * pdx + pdy * pdy + pdz * pdz;
            float td2 = tdx * tdx + tdy * tdy + tdz * tdz;
            float pinv = (pd2 > 0.f) ? fast_rsq(pd2) : 0.f;
            float tinv = (td2 > 0.f) ? fast_rsq(td2) : 0.f;
            float dx = pdx * pinv - tdx * tinv;
            float dy = pdy * pinv - tdy * tinv;
            float dz = pdz * pinv - tdz * tinv;
            float m0 = (mg0 != 0.f) ? act[j] : 0.f;
            float m1 = (mg1 != 0.f) ? act[j] : 0.f;
            float m2 = (mg2 != 0.f) ? act[j] : 0.f;
            vel += m0 * dx * dx + m1 * dy * dy + m2 * dz * dz;
        }
    }

    // ---- block reduction -> per-block partials ----
#pragma unroll
    for (int off = 32; off > 0; off >>= 1) {
        l1  += __shfl_down(l1, off);
        vel += __shfl_down(vel, off);
    }
    if (lane == 0) { redL[wave] = l1; redV[wave] = vel; }
    __syncthreads();
    if (t == 0) {
        wsL[blockIdx.x] = redL[0] + redL[1] + redL[2] + redL[3];
        wsV[blockIdx.x] = redV[0] + redV[1] + redV[2] + redV[3];
    }
}

__global__ __launch_bounds__(BLOCK) void reg_loss_finalize(
        const float* __restrict__ wsL, const float* __restrict__ wsV,
        float* __restrict__ out) {
    __shared__ double rl[4], rv[4];
    const int t = threadIdx.x;
    const int lane = t & 63;
    const int wave = t >> 6;
    double L = 0.0, V = 0.0;
    for (int k = t; k < GRID; k += BLOCK) { L += wsL[k]; V += wsV[k]; }
#pragma unroll
    for (int off = 32; off > 0; off >>= 1) {
        L += __shfl_down(L, off);
        V += __shfl_down(V, off);
    }
    if (lane == 0) { rl[wave] = L; rv[wave] = V; }
    __syncthreads();
    if (t == 0) {
        double Ls = rl[0] + rl[1] + rl[2] + rl[3];
        double Vs = rv[0] + rv[1] + rv[2] + rv[3];
        out[0] = (float)(Ls / ((double)N_ROWS * 151.0)
                       + 0.1 * (Vs / ((double)N_ROWS * 141.0)));
    }
}

extern "C" void kernel_launch(void* const* d_in, const int* in_sizes, int n_in,
                              void* d_out, int out_size, void* d_ws, size_t ws_size,
                              hipStream_t stream) {
    const float* preds   = (const float*)d_in[0];
    const float* targets = (const float*)d_in[1];
    float* wsL = (float*)d_ws;
    float* wsV = wsL + GRID;
    float* out = (float*)d_out;

    reg_loss_main<<<GRID, BLOCK, 0, stream>>>(preds, targets, wsL, wsV);
    reg_loss_finalize<<<1, BLOCK, 0, stream>>>(wsL, wsV, out);
}